// Round 1
// baseline (1005.011 us; speedup 1.0000x reference)
//
#include <hip/hip_runtime.h>

#define D 64
#define EPS 1e-5f

// deg init to 1.0 (self-loop weight), zero the stats accumulator
__global__ void k_init(float* __restrict__ deg, float* __restrict__ stats, int n) {
    int i = blockIdx.x * 256 + threadIdx.x;
    if (i < n) deg[i] = 1.0f;
    if (i < 128) stats[i] = 0.0f;
}

// weighted in-degree: deg[dst] += w
__global__ void k_deg(const int* __restrict__ dst, const float* __restrict__ w,
                      float* __restrict__ deg, int E) {
    int e = blockIdx.x * 256 + threadIdx.x;
    if (e < E) atomicAdd(&deg[dst[e]], w[e]);
}

// deg -> rsqrt(deg)  (deg >= 1 always, self-loop)
__global__ void k_dinv(float* __restrict__ deg, int n) {
    int i = blockIdx.x * 256 + threadIdx.x;
    if (i < n) deg[i] = rsqrtf(deg[i]);
}

// out = x @ W, optionally with fused BN(scale,shift)+ReLU applied to x rows.
// One wave per node (lane j computes column j); W staged in LDS.
template <bool BN>
__global__ void k_gemm(const float* __restrict__ x, const float* __restrict__ W,
                       const float* __restrict__ stats, float* __restrict__ out, int n) {
    __shared__ float Wl[D][D];   // Wl[k][j]
    __shared__ float xs[4][D];
    int tid = threadIdx.x;
    int j   = tid & 63;
    int ns  = tid >> 6;          // wave id 0..3 -> node slot
    for (int t = tid; t < D * D; t += 256) Wl[t >> 6][t & 63] = W[t];
    float scale = 0.f, shift = 0.f;
    if (BN) { scale = stats[j]; shift = stats[64 + j]; }
    __syncthreads();
    for (int base = blockIdx.x * 4; base < n; base += gridDim.x * 4) {
        int node = base + ns;
        float v = 0.f;
        if (node < n) {
            v = x[node * D + j];
            if (BN) v = fmaxf(fmaf(v, scale, shift), 0.f);
        }
        __syncthreads();          // previous iteration's xs reads done
        xs[ns][j] = v;
        __syncthreads();
        if (node < n) {
            float acc = 0.f;
#pragma unroll
            for (int k = 0; k < D; ++k) acc = fmaf(xs[ns][k], Wl[k][j], acc);
            out[node * D + j] = acc;
        }
    }
}

// out[i] = h[i]*dinv[i]^2 (+ bias)  — self-loop contribution + optional bias
__global__ void k_selfinit(const float* __restrict__ h, const float* __restrict__ dinv,
                           const float* __restrict__ bias, float* __restrict__ out, int n) {
    int idx = blockIdx.x * 256 + threadIdx.x;
    if (idx < n * D) {
        int i = idx >> 6, j = idx & 63;
        float di = dinv[i];
        float v  = h[idx] * di * di;
        if (bias) v += bias[j];
        out[idx] = v;
    }
}

// scatter: out[dst] += h[src] * (dinv[src]*w*dinv[dst]) ; one wave per edge
__global__ void k_edge(const float* __restrict__ h, const int* __restrict__ src,
                       const int* __restrict__ dst, const float* __restrict__ w,
                       const float* __restrict__ dinv, float* __restrict__ out, int E) {
    int e = blockIdx.x * 4 + (threadIdx.x >> 6);
    if (e >= E) return;
    int j = threadIdx.x & 63;
    int s = src[e], d = dst[e];
    float nrm = dinv[s] * w[e] * dinv[d];
    atomicAdd(&out[d * D + j], h[s * D + j] * nrm);
}

// per-column sum / sumsq of a[n][64] -> stats[0:64], stats[64:128]
__global__ void k_stats(const float* __restrict__ a, float* __restrict__ stats, int n) {
    int j  = threadIdx.x & 63;
    int wv = threadIdx.x >> 6;
    float s = 0.f, q = 0.f;
    for (int i = blockIdx.x * 4 + wv; i < n; i += gridDim.x * 4) {
        float v = a[i * D + j];
        s += v;
        q = fmaf(v, v, q);
    }
    __shared__ float ls[4][64];
    __shared__ float lq[4][64];
    ls[wv][j] = s;
    lq[wv][j] = q;
    __syncthreads();
    if (threadIdx.x < 64) {
        atomicAdd(&stats[j],      ls[0][j] + ls[1][j] + ls[2][j] + ls[3][j]);
        atomicAdd(&stats[64 + j], lq[0][j] + lq[1][j] + lq[2][j] + lq[3][j]);
    }
}

// stats -> (scale, shift):  scale = gamma*rsqrt(var+eps), shift = beta - mean*scale
// (b1 cancels: BN subtracts the column mean, so it never enters.)
__global__ void k_finalize(float* __restrict__ stats, const float* __restrict__ gamma,
                           const float* __restrict__ beta, float inv_n) {
    int j = threadIdx.x;
    if (j < 64) {
        float mean = stats[j] * inv_n;
        float var  = stats[64 + j] * inv_n - mean * mean;
        float sc   = gamma[j] * rsqrtf(var + EPS);
        stats[j]      = sc;
        stats[64 + j] = beta[j] - mean * sc;
    }
}

extern "C" void kernel_launch(void* const* d_in, const int* in_sizes, int n_in,
                              void* d_out, int out_size, void* d_ws, size_t ws_size,
                              hipStream_t stream) {
    const float* x     = (const float*)d_in[0];
    const int*   ei    = (const int*)d_in[1];
    const float* ew    = (const float*)d_in[2];
    const float* W1    = (const float*)d_in[3];
    // d_in[4] = b1 : cancels exactly in BatchNorm (mean-subtracted) — unused.
    const float* gamma = (const float*)d_in[5];
    const float* beta  = (const float*)d_in[6];
    const float* W2    = (const float*)d_in[7];
    const float* b2    = (const float*)d_in[8];
    float*       out   = (float*)d_out;

    const int N = in_sizes[0] / D;
    const int E = in_sizes[2];
    const int* src = ei;
    const int* dst = ei + E;

    float* h1    = (float*)d_ws;              // N*D
    float* agg1  = h1 + (size_t)N * D;        // N*D
    float* dinv  = agg1 + (size_t)N * D;      // N   (holds deg, then rsqrt in place)
    float* stats = dinv + N;                  // 128 (sum/sumsq, then scale/shift)

    const int nb_n  = (N + 255) / 256;
    const int nb_e  = (E + 255) / 256;
    const int nb_nd = (N * D + 255) / 256;
    const int nb_ew = (E + 3) / 4;            // one wave per edge

    k_init<<<nb_n, 256, 0, stream>>>(dinv, stats, N);
    k_deg<<<nb_e, 256, 0, stream>>>(dst, ew, dinv, E);
    k_dinv<<<nb_n, 256, 0, stream>>>(dinv, N);

    k_gemm<false><<<2048, 256, 0, stream>>>(x, W1, nullptr, h1, N);

    k_selfinit<<<nb_nd, 256, 0, stream>>>(h1, dinv, nullptr, agg1, N);
    k_edge<<<nb_ew, 256, 0, stream>>>(h1, src, dst, ew, dinv, agg1, E);

    k_stats<<<512, 256, 0, stream>>>(agg1, stats, N);
    k_finalize<<<1, 64, 0, stream>>>(stats, gamma, beta, 1.0f / (float)N);

    // h2 = relu(BN(agg1)) @ W2  — overwrites h1 (no longer needed)
    k_gemm<true><<<2048, 256, 0, stream>>>(agg1, W2, stats, h1, N);

    k_selfinit<<<nb_nd, 256, 0, stream>>>(h1, dinv, b2, out, N);
    k_edge<<<nb_ew, 256, 0, stream>>>(h1, src, dst, ew, dinv, out, E);
}

// Round 5
// 737.373 us; speedup vs baseline: 1.3630x; 1.3630x over previous
//
#include <hip/hip_runtime.h>

#define D 64
#define EPS 1e-5f

// deg=1.0 (self-loop), cnt=0, stats=0
__global__ void k_init(float* __restrict__ deg, int* __restrict__ cnt,
                       float* __restrict__ stats, int n) {
    int i = blockIdx.x * 256 + threadIdx.x;
    if (i < n) { deg[i] = 1.0f; cnt[i] = 0; }
    if (i < 128) stats[i] = 0.0f;
}

// weighted in-degree + edge count per dst
__global__ void k_degcnt(const int* __restrict__ dst, const float* __restrict__ w,
                         float* __restrict__ deg, int* __restrict__ cnt, int E) {
    int e = blockIdx.x * 256 + threadIdx.x;
    if (e < E) {
        int d = dst[e];
        atomicAdd(&deg[d], w[e]);
        atomicAdd(&cnt[d], 1);
    }
}

__global__ void k_dinv(float* __restrict__ deg, int n) {
    int i = blockIdx.x * 256 + threadIdx.x;
    if (i < n) deg[i] = rsqrtf(deg[i]);
}

// ---- exclusive scan of cnt[N] -> rowptr[N+1] (3 kernels) ----
__global__ void k_scan1(const int* __restrict__ cnt, int* __restrict__ incl,
                        int* __restrict__ bsum, int n) {
    __shared__ int sm[256];
    int i = blockIdx.x * 256 + threadIdx.x;
    int v = (i < n) ? cnt[i] : 0;
    sm[threadIdx.x] = v;
    __syncthreads();
    for (int off = 1; off < 256; off <<= 1) {
        int t = 0;
        if (threadIdx.x >= off) t = sm[threadIdx.x - off];
        __syncthreads();
        if (threadIdx.x >= off) sm[threadIdx.x] += t;
        __syncthreads();
    }
    if (i < n) incl[i] = sm[threadIdx.x];
    if (threadIdx.x == 255) bsum[blockIdx.x] = sm[255];
}

__global__ void k_scan2(int* __restrict__ bsum, int nb) {
    __shared__ int sm[512];
    int v = (threadIdx.x < nb) ? bsum[threadIdx.x] : 0;
    sm[threadIdx.x] = v;
    __syncthreads();
    for (int off = 1; off < 512; off <<= 1) {
        int t = 0;
        if (threadIdx.x >= off) t = sm[threadIdx.x - off];
        __syncthreads();
        if (threadIdx.x >= off) sm[threadIdx.x] += t;
        __syncthreads();
    }
    if (threadIdx.x < nb) bsum[threadIdx.x] = sm[threadIdx.x] - v;  // exclusive
}

__global__ void k_scan3(const int* __restrict__ cnt, const int* __restrict__ incl,
                        const int* __restrict__ boff, int* __restrict__ rowptr,
                        int* __restrict__ cursor, int n, int E) {
    int i = blockIdx.x * 256 + threadIdx.x;
    if (i < n) {
        int ex = incl[i] - cnt[i] + boff[blockIdx.x];
        rowptr[i] = ex;
        cursor[i] = ex;
        if (i == n - 1) rowptr[n] = E;
    }
}

// fill CSR payload: edata[p] = (src_bits, dinv[s]*w*dinv[d]) grouped by dst
__global__ void k_fill(const int* __restrict__ src, const int* __restrict__ dst,
                       const float* __restrict__ w, const float* __restrict__ dinv,
                       int* __restrict__ cursor, float2* __restrict__ edata, int E) {
    int e = blockIdx.x * 256 + threadIdx.x;
    if (e < E) {
        int s = src[e], d = dst[e];
        int p = atomicAdd(&cursor[d], 1);
        edata[p] = make_float2(__int_as_float(s), dinv[s] * w[e] * dinv[d]);
    }
}

// out = x @ W, optionally with fused BN(scale,shift)+ReLU applied to x rows.
// One wave per node (lane j computes column j); W staged in LDS.
template <bool BN>
__global__ void k_gemm(const float* __restrict__ x, const float* __restrict__ W,
                       const float* __restrict__ stats, float* __restrict__ out, int n) {
    __shared__ float Wl[D][D];   // Wl[k][j]
    __shared__ float xs[4][D];
    int tid = threadIdx.x;
    int j   = tid & 63;
    int ns  = tid >> 6;
    for (int t = tid; t < D * D; t += 256) Wl[t >> 6][t & 63] = W[t];
    float scale = 0.f, shift = 0.f;
    if (BN) { scale = stats[j]; shift = stats[64 + j]; }
    __syncthreads();
    for (int base = blockIdx.x * 4; base < n; base += gridDim.x * 4) {
        int node = base + ns;
        float v = 0.f;
        if (node < n) {
            v = x[node * D + j];
            if (BN) v = fmaxf(fmaf(v, scale, shift), 0.f);
        }
        __syncthreads();
        xs[ns][j] = v;
        __syncthreads();
        if (node < n) {
            float acc = 0.f;
#pragma unroll
            for (int k = 0; k < D; ++k) acc = fmaf(xs[ns][k], Wl[k][j], acc);
            out[node * D + j] = acc;
        }
    }
}

// gather-accumulate per dst node: self-loop + bias + CSR edges; optional BN stats
template <bool STATS>
__global__ void k_agg(const float* __restrict__ h, const float2* __restrict__ edata,
                      const int* __restrict__ rowptr, const float* __restrict__ dinv,
                      const float* __restrict__ bias, float* __restrict__ out,
                      float* __restrict__ stats, int n) {
    int j  = threadIdx.x & 63;
    int wv = threadIdx.x >> 6;
    float s = 0.f, q = 0.f;
    for (int d = blockIdx.x * 4 + wv; d < n; d += gridDim.x * 4) {
        float di  = dinv[d];
        float acc = h[d * D + j] * di * di;
        if (bias) acc += bias[j];
        int k1 = rowptr[d + 1];
        for (int k = rowptr[d]; k < k1; ++k) {
            float2 md = edata[k];
            acc = fmaf(h[__float_as_int(md.x) * D + j], md.y, acc);
        }
        out[d * D + j] = acc;
        if (STATS) { s += acc; q = fmaf(acc, acc, q); }
    }
    if (STATS) {
        __shared__ float ls[4][64];
        __shared__ float lq[4][64];
        ls[wv][j] = s;
        lq[wv][j] = q;
        __syncthreads();
        if (threadIdx.x < 64) {
            atomicAdd(&stats[j],      ls[0][j] + ls[1][j] + ls[2][j] + ls[3][j]);
            atomicAdd(&stats[64 + j], lq[0][j] + lq[1][j] + lq[2][j] + lq[3][j]);
        }
    }
}

// stats -> (scale, shift):  scale = gamma*rsqrt(var+eps), shift = beta - mean*scale
// (b1 cancels: BN subtracts the column mean.)
__global__ void k_finalize(float* __restrict__ stats, const float* __restrict__ gamma,
                           const float* __restrict__ beta, float inv_n) {
    int j = threadIdx.x;
    if (j < 64) {
        float mean = stats[j] * inv_n;
        float var  = stats[64 + j] * inv_n - mean * mean;
        float sc   = gamma[j] * rsqrtf(var + EPS);
        stats[j]      = sc;
        stats[64 + j] = beta[j] - mean * sc;
    }
}

extern "C" void kernel_launch(void* const* d_in, const int* in_sizes, int n_in,
                              void* d_out, int out_size, void* d_ws, size_t ws_size,
                              hipStream_t stream) {
    const float* x     = (const float*)d_in[0];
    const int*   ei    = (const int*)d_in[1];
    const float* ew    = (const float*)d_in[2];
    const float* W1    = (const float*)d_in[3];
    // d_in[4] = b1 : cancels exactly in BatchNorm — unused.
    const float* gamma = (const float*)d_in[5];
    const float* beta  = (const float*)d_in[6];
    const float* W2    = (const float*)d_in[7];
    const float* b2    = (const float*)d_in[8];
    float*       out   = (float*)d_out;

    const int N = in_sizes[0] / D;
    const int E = in_sizes[2];
    const int* src = ei;
    const int* dst = ei + E;

    // ws layout (edata first for 8B alignment)
    float2* edata  = (float2*)d_ws;                    // E float2
    float*  h1     = (float*)(edata + E);              // N*D
    float*  agg1   = h1 + (size_t)N * D;               // N*D
    float*  dinv   = agg1 + (size_t)N * D;             // N
    float*  stats  = dinv + N;                         // 128
    int*    cnt    = (int*)(stats + 128);              // N
    int*    rowptr = cnt + N;                          // N+1
    int*    cursor = rowptr + N + 1;                   // N   (also incl-scan temp)
    int*    bsum   = cursor + N;                       // 512

    const int nb_n = (N + 255) / 256;
    const int nb_e = (E + 255) / 256;

    k_init<<<nb_n, 256, 0, stream>>>(dinv, cnt, stats, N);
    k_degcnt<<<nb_e, 256, 0, stream>>>(dst, ew, dinv, cnt, E);
    k_dinv<<<nb_n, 256, 0, stream>>>(dinv, N);

    k_scan1<<<nb_n, 256, 0, stream>>>(cnt, cursor, bsum, N);   // cursor holds incl
    k_scan2<<<1, 512, 0, stream>>>(bsum, nb_n);
    k_scan3<<<nb_n, 256, 0, stream>>>(cnt, cursor, bsum, rowptr, cursor, N, E);
    k_fill<<<nb_e, 256, 0, stream>>>(src, dst, ew, dinv, cursor, edata, E);

    k_gemm<false><<<2048, 256, 0, stream>>>(x, W1, nullptr, h1, N);
    k_agg<true><<<2048, 256, 0, stream>>>(h1, edata, rowptr, dinv, nullptr, agg1, stats, N);
    k_finalize<<<1, 64, 0, stream>>>(stats, gamma, beta, 1.0f / (float)N);

    // h2 = relu(BN(agg1)) @ W2 — overwrites h1
    k_gemm<true><<<2048, 256, 0, stream>>>(agg1, W2, stats, h1, N);
    k_agg<false><<<2048, 256, 0, stream>>>(h1, edata, rowptr, dinv, b2, out, nullptr, N);
}

// Round 8
// 619.541 us; speedup vs baseline: 1.6222x; 1.1902x over previous
//
#include <hip/hip_runtime.h>

#define D 64
#define EPS 1e-5f

// deg=1.0 (self-loop), cnt=0, stats=0
__global__ void k_init(float* __restrict__ deg, int* __restrict__ cnt,
                       float* __restrict__ stats, int n) {
    int i = blockIdx.x * 256 + threadIdx.x;
    if (i < n) { deg[i] = 1.0f; cnt[i] = 0; }
    if (i < 128) stats[i] = 0.0f;
}

// weighted in-degree + edge count per dst
__global__ void k_degcnt(const int* __restrict__ dst, const float* __restrict__ w,
                         float* __restrict__ deg, int* __restrict__ cnt, int E) {
    int e = blockIdx.x * 256 + threadIdx.x;
    if (e < E) {
        int d = dst[e];
        atomicAdd(&deg[d], w[e]);
        atomicAdd(&cnt[d], 1);
    }
}

__global__ void k_dinv(float* __restrict__ deg, int n) {
    int i = blockIdx.x * 256 + threadIdx.x;
    if (i < n) deg[i] = rsqrtf(deg[i]);
}

// ---- exclusive scan of cnt[N] -> rowptr[N+1] (3 kernels) ----
__global__ void k_scan1(const int* __restrict__ cnt, int* __restrict__ incl,
                        int* __restrict__ bsum, int n) {
    __shared__ int sm[256];
    int i = blockIdx.x * 256 + threadIdx.x;
    int v = (i < n) ? cnt[i] : 0;
    sm[threadIdx.x] = v;
    __syncthreads();
    for (int off = 1; off < 256; off <<= 1) {
        int t = 0;
        if (threadIdx.x >= off) t = sm[threadIdx.x - off];
        __syncthreads();
        if (threadIdx.x >= off) sm[threadIdx.x] += t;
        __syncthreads();
    }
    if (i < n) incl[i] = sm[threadIdx.x];
    if (threadIdx.x == 255) bsum[blockIdx.x] = sm[255];
}

__global__ void k_scan2(int* __restrict__ bsum, int nb) {
    __shared__ int sm[512];
    int v = (threadIdx.x < nb) ? bsum[threadIdx.x] : 0;
    sm[threadIdx.x] = v;
    __syncthreads();
    for (int off = 1; off < 512; off <<= 1) {
        int t = 0;
        if (threadIdx.x >= off) t = sm[threadIdx.x - off];
        __syncthreads();
        if (threadIdx.x >= off) sm[threadIdx.x] += t;
        __syncthreads();
    }
    if (threadIdx.x < nb) bsum[threadIdx.x] = sm[threadIdx.x] - v;  // exclusive
}

__global__ void k_scan3(const int* __restrict__ cnt, const int* __restrict__ incl,
                        const int* __restrict__ boff, int* __restrict__ rowptr,
                        int* __restrict__ cursor, int n, int E) {
    int i = blockIdx.x * 256 + threadIdx.x;
    if (i < n) {
        int ex = incl[i] - cnt[i] + boff[blockIdx.x];
        rowptr[i] = ex;
        cursor[i] = ex;
        if (i == n - 1) rowptr[n] = E;
    }
}

// fill CSR payload: edata[p] = (src_bits, dinv[s]*w*dinv[d]) grouped by dst
__global__ void k_fill(const int* __restrict__ src, const int* __restrict__ dst,
                       const float* __restrict__ w, const float* __restrict__ dinv,
                       int* __restrict__ cursor, float2* __restrict__ edata, int E) {
    int e = blockIdx.x * 256 + threadIdx.x;
    if (e < E) {
        int s = src[e], d = dst[e];
        int p = atomicAdd(&cursor[d], 1);
        edata[p] = make_float2(__int_as_float(s), dinv[s] * w[e] * dinv[d]);
    }
}

// out = x @ W, optionally with fused BN(scale,shift)+ReLU applied to x rows.
// One wave per node (lane j computes column j); W staged in LDS.
template <bool BN>
__global__ void k_gemm(const float* __restrict__ x, const float* __restrict__ W,
                       const float* __restrict__ stats, float* __restrict__ out, int n) {
    __shared__ float Wl[D][D];   // Wl[k][j]
    __shared__ float xs[4][D];
    int tid = threadIdx.x;
    int j   = tid & 63;
    int ns  = tid >> 6;
    for (int t = tid; t < D * D; t += 256) Wl[t >> 6][t & 63] = W[t];
    float scale = 0.f, shift = 0.f;
    if (BN) { scale = stats[j]; shift = stats[64 + j]; }
    __syncthreads();
    for (int base = blockIdx.x * 4; base < n; base += gridDim.x * 4) {
        int node = base + ns;
        float v = 0.f;
        if (node < n) {
            v = x[node * D + j];
            if (BN) v = fmaxf(fmaf(v, scale, shift), 0.f);
        }
        __syncthreads();
        xs[ns][j] = v;
        __syncthreads();
        if (node < n) {
            float acc = 0.f;
#pragma unroll
            for (int k = 0; k < D; ++k) acc = fmaf(xs[ns][k], Wl[k][j], acc);
            out[node * D + j] = acc;
        }
    }
}

// gather-accumulate per dst node: self-loop + bias + CSR edges; optional BN stats.
// 2 nodes per wave (half-wave each, float2 per lane), edge loop unrolled x4
// for ~8 outstanding gathers per wave (latency hiding).
template <bool STATS>
__global__ void k_agg(const float* __restrict__ h, const float2* __restrict__ edata,
                      const int* __restrict__ rowptr, const float* __restrict__ dinv,
                      const float* __restrict__ bias, float* __restrict__ out,
                      float* __restrict__ stats, int n) {
    const float2* hp = (const float2*)h;
    float2*       op = (float2*)out;
    int tid  = threadIdx.x;
    int wv   = tid >> 6;          // wave 0..3
    int lane = tid & 63;
    int half = lane >> 5;         // 0,1 -> node slot within wave
    int l    = lane & 31;         // float2 column index (cols 2l, 2l+1)
    float2 bb = make_float2(0.f, 0.f);
    if (bias) bb = ((const float2*)bias)[l];
    float2 s = make_float2(0.f, 0.f), q = make_float2(0.f, 0.f);

    for (int d0 = blockIdx.x * 8; d0 < n; d0 += gridDim.x * 8) {
        int d = d0 + wv * 2 + half;
        if (d < n) {
            float di  = dinv[d];
            float sl  = di * di;
            float2 acc = hp[d * 32 + l];
            acc.x = fmaf(acc.x, sl, bb.x);
            acc.y = fmaf(acc.y, sl, bb.y);
            int k  = rowptr[d];
            int k1 = rowptr[d + 1];
            for (; k + 4 <= k1; k += 4) {
                float2 m0 = edata[k + 0];
                float2 m1 = edata[k + 1];
                float2 m2 = edata[k + 2];
                float2 m3 = edata[k + 3];
                float2 a0 = hp[__float_as_int(m0.x) * 32 + l];
                float2 a1 = hp[__float_as_int(m1.x) * 32 + l];
                float2 a2 = hp[__float_as_int(m2.x) * 32 + l];
                float2 a3 = hp[__float_as_int(m3.x) * 32 + l];
                acc.x = fmaf(a0.x, m0.y, acc.x); acc.y = fmaf(a0.y, m0.y, acc.y);
                acc.x = fmaf(a1.x, m1.y, acc.x); acc.y = fmaf(a1.y, m1.y, acc.y);
                acc.x = fmaf(a2.x, m2.y, acc.x); acc.y = fmaf(a2.y, m2.y, acc.y);
                acc.x = fmaf(a3.x, m3.y, acc.x); acc.y = fmaf(a3.y, m3.y, acc.y);
            }
            for (; k < k1; ++k) {
                float2 m = edata[k];
                float2 a = hp[__float_as_int(m.x) * 32 + l];
                acc.x = fmaf(a.x, m.y, acc.x);
                acc.y = fmaf(a.y, m.y, acc.y);
            }
            op[d * 32 + l] = acc;
            if (STATS) {
                s.x += acc.x; s.y += acc.y;
                q.x = fmaf(acc.x, acc.x, q.x);
                q.y = fmaf(acc.y, acc.y, q.y);
            }
        }
    }
    if (STATS) {
        __shared__ float2 ls[4][2][32];
        __shared__ float2 lq[4][2][32];
        ls[wv][half][l] = s;
        lq[wv][half][l] = q;
        __syncthreads();
        if (tid < 32) {
            float2 S = make_float2(0.f, 0.f), Q = make_float2(0.f, 0.f);
#pragma unroll
            for (int w2 = 0; w2 < 4; ++w2)
#pragma unroll
                for (int hh = 0; hh < 2; ++hh) {
                    S.x += ls[w2][hh][tid].x; S.y += ls[w2][hh][tid].y;
                    Q.x += lq[w2][hh][tid].x; Q.y += lq[w2][hh][tid].y;
                }
            atomicAdd(&stats[2 * tid],     S.x);
            atomicAdd(&stats[2 * tid + 1], S.y);
            atomicAdd(&stats[64 + 2 * tid],     Q.x);
            atomicAdd(&stats[64 + 2 * tid + 1], Q.y);
        }
    }
}

// stats -> (scale, shift):  scale = gamma*rsqrt(var+eps), shift = beta - mean*scale
// (b1 cancels: BN subtracts the column mean.)
__global__ void k_finalize(float* __restrict__ stats, const float* __restrict__ gamma,
                           const float* __restrict__ beta, float inv_n) {
    int j = threadIdx.x;
    if (j < 64) {
        float mean = stats[j] * inv_n;
        float var  = stats[64 + j] * inv_n - mean * mean;
        float sc   = gamma[j] * rsqrtf(var + EPS);
        stats[j]      = sc;
        stats[64 + j] = beta[j] - mean * sc;
    }
}

extern "C" void kernel_launch(void* const* d_in, const int* in_sizes, int n_in,
                              void* d_out, int out_size, void* d_ws, size_t ws_size,
                              hipStream_t stream) {
    const float* x     = (const float*)d_in[0];
    const int*   ei    = (const int*)d_in[1];
    const float* ew    = (const float*)d_in[2];
    const float* W1    = (const float*)d_in[3];
    // d_in[4] = b1 : cancels exactly in BatchNorm — unused.
    const float* gamma = (const float*)d_in[5];
    const float* beta  = (const float*)d_in[6];
    const float* W2    = (const float*)d_in[7];
    const float* b2    = (const float*)d_in[8];
    float*       out   = (float*)d_out;

    const int N = in_sizes[0] / D;
    const int E = in_sizes[2];
    const int* src = ei;
    const int* dst = ei + E;

    // ws layout (edata first for 8B alignment)
    float2* edata  = (float2*)d_ws;                    // E float2
    float*  h1     = (float*)(edata + E);              // N*D
    float*  agg1   = h1 + (size_t)N * D;               // N*D
    float*  dinv   = agg1 + (size_t)N * D;             // N
    float*  stats  = dinv + N;                         // 128
    int*    cnt    = (int*)(stats + 128);              // N
    int*    rowptr = cnt + N;                          // N+1
    int*    cursor = rowptr + N + 1;                   // N   (also incl-scan temp)
    int*    bsum   = cursor + N;                       // 512

    const int nb_n = (N + 255) / 256;
    const int nb_e = (E + 255) / 256;

    k_init<<<nb_n, 256, 0, stream>>>(dinv, cnt, stats, N);
    k_degcnt<<<nb_e, 256, 0, stream>>>(dst, ew, dinv, cnt, E);
    k_dinv<<<nb_n, 256, 0, stream>>>(dinv, N);

    k_scan1<<<nb_n, 256, 0, stream>>>(cnt, cursor, bsum, N);   // cursor holds incl
    k_scan2<<<1, 512, 0, stream>>>(bsum, nb_n);
    k_scan3<<<nb_n, 256, 0, stream>>>(cnt, cursor, bsum, rowptr, cursor, N, E);
    k_fill<<<nb_e, 256, 0, stream>>>(src, dst, ew, dinv, cursor, edata, E);

    k_gemm<false><<<2048, 256, 0, stream>>>(x, W1, nullptr, h1, N);
    k_agg<true><<<2048, 256, 0, stream>>>(h1, edata, rowptr, dinv, nullptr, agg1, stats, N);
    k_finalize<<<1, 64, 0, stream>>>(stats, gamma, beta, 1.0f / (float)N);

    // h2 = relu(BN(agg1)) @ W2 — overwrites h1
    k_gemm<true><<<2048, 256, 0, stream>>>(agg1, W2, stats, h1, N);
    k_agg<false><<<2048, 256, 0, stream>>>(h1, edata, rowptr, dinv, b2, out, nullptr, N);
}

// Round 9
// 566.044 us; speedup vs baseline: 1.7755x; 1.0945x over previous
//
#include <hip/hip_runtime.h>

#define D 64
#define EPS 1e-5f

// RTNE float->bf16 (finite values)
static __device__ __forceinline__ unsigned f2bf(float f) {
    unsigned u = __float_as_uint(f);
    unsigned r = ((u >> 16) & 1u) + 0x7fffu;
    return (u + r) >> 16;
}

// deg=1.0 (self-loop), cnt=0, stats=0
__global__ void k_init(float* __restrict__ deg, int* __restrict__ cnt,
                       float* __restrict__ stats, int n) {
    int i = blockIdx.x * 256 + threadIdx.x;
    if (i < n) { deg[i] = 1.0f; cnt[i] = 0; }
    if (i < 128) stats[i] = 0.0f;
}

// weighted in-degree + edge count per dst
__global__ void k_degcnt(const int* __restrict__ dst, const float* __restrict__ w,
                         float* __restrict__ deg, int* __restrict__ cnt, int E) {
    int e = blockIdx.x * 256 + threadIdx.x;
    if (e < E) {
        int d = dst[e];
        atomicAdd(&deg[d], w[e]);
        atomicAdd(&cnt[d], 1);
    }
}

__global__ void k_dinv(float* __restrict__ deg, int n) {
    int i = blockIdx.x * 256 + threadIdx.x;
    if (i < n) deg[i] = rsqrtf(deg[i]);
}

// ---- exclusive scan of cnt[N] -> rowptr[N+1] (3 kernels) ----
__global__ void k_scan1(const int* __restrict__ cnt, int* __restrict__ incl,
                        int* __restrict__ bsum, int n) {
    __shared__ int sm[256];
    int i = blockIdx.x * 256 + threadIdx.x;
    int v = (i < n) ? cnt[i] : 0;
    sm[threadIdx.x] = v;
    __syncthreads();
    for (int off = 1; off < 256; off <<= 1) {
        int t = 0;
        if (threadIdx.x >= off) t = sm[threadIdx.x - off];
        __syncthreads();
        if (threadIdx.x >= off) sm[threadIdx.x] += t;
        __syncthreads();
    }
    if (i < n) incl[i] = sm[threadIdx.x];
    if (threadIdx.x == 255) bsum[blockIdx.x] = sm[255];
}

__global__ void k_scan2(int* __restrict__ bsum, int nb) {
    __shared__ int sm[512];
    int v = (threadIdx.x < nb) ? bsum[threadIdx.x] : 0;
    sm[threadIdx.x] = v;
    __syncthreads();
    for (int off = 1; off < 512; off <<= 1) {
        int t = 0;
        if (threadIdx.x >= off) t = sm[threadIdx.x - off];
        __syncthreads();
        if (threadIdx.x >= off) sm[threadIdx.x] += t;
        __syncthreads();
    }
    if (threadIdx.x < nb) bsum[threadIdx.x] = sm[threadIdx.x] - v;  // exclusive
}

__global__ void k_scan3(const int* __restrict__ cnt, const int* __restrict__ incl,
                        const int* __restrict__ boff, int* __restrict__ rowptr,
                        int* __restrict__ cursor, int n, int E) {
    int i = blockIdx.x * 256 + threadIdx.x;
    if (i < n) {
        int ex = incl[i] - cnt[i] + boff[blockIdx.x];
        rowptr[i] = ex;
        cursor[i] = ex;
        if (i == n - 1) rowptr[n] = E;
    }
}

// fill CSR payload: edata[p] = (src_bits, dinv[s]*w*dinv[d]) grouped by dst
__global__ void k_fill(const int* __restrict__ src, const int* __restrict__ dst,
                       const float* __restrict__ w, const float* __restrict__ dinv,
                       int* __restrict__ cursor, float2* __restrict__ edata, int E) {
    int e = blockIdx.x * 256 + threadIdx.x;
    if (e < E) {
        int s = src[e], d = dst[e];
        int p = atomicAdd(&cursor[d], 1);
        edata[p] = make_float2(__int_as_float(s), dinv[s] * w[e] * dinv[d]);
    }
}

// out = x @ W -> packed bf16x2 rows (32 uints per node), optionally with fused
// BN(scale,shift)+ReLU on input rows. Each thread computes 2 adjacent columns;
// 8 nodes per block-iteration.
template <bool BN>
__global__ void k_gemm(const float* __restrict__ x, const float* __restrict__ W,
                       const float* __restrict__ stats, unsigned* __restrict__ outb,
                       int n) {
    __shared__ float Wl[D][D];     // Wl[k][j]
    __shared__ float xs[8][D];
    int tid = threadIdx.x;
    int l   = tid & 31;            // column pair index (cols 2l, 2l+1)
    int ns  = tid >> 5;            // node slot 0..7
    for (int t = tid; t < D * D; t += 256) Wl[t >> 6][t & 63] = W[t];
    __syncthreads();
    for (int base = blockIdx.x * 8; base < n; base += gridDim.x * 8) {
        __syncthreads();           // previous iteration's xs reads done
        for (int t = tid; t < 8 * D; t += 256) {
            int r = t >> 6, c = t & 63;
            int node = base + r;
            float v = 0.f;
            if (node < n) {
                v = x[node * D + c];
                if (BN) v = fmaxf(fmaf(v, stats[c], stats[64 + c]), 0.f);
            }
            xs[r][c] = v;
        }
        __syncthreads();
        int node = base + ns;
        if (node < n) {
            float a0 = 0.f, a1 = 0.f;
#pragma unroll
            for (int k = 0; k < D; ++k) {
                float xv  = xs[ns][k];
                float2 wp = ((const float2*)Wl[k])[l];
                a0 = fmaf(xv, wp.x, a0);
                a1 = fmaf(xv, wp.y, a1);
            }
            outb[node * 32 + l] = f2bf(a0) | (f2bf(a1) << 16);
        }
    }
}

// gather-accumulate per dst node from packed-bf16 h: self-loop + bias + CSR
// edges; optional BN stats. 2 nodes per wave (half-wave each, one uint = 2
// bf16 cols per lane), edge loop unrolled x4.
template <bool STATS>
__global__ void k_agg(const unsigned* __restrict__ hb, const float2* __restrict__ edata,
                      const int* __restrict__ rowptr, const float* __restrict__ dinv,
                      const float* __restrict__ bias, float* __restrict__ out,
                      float* __restrict__ stats, int n) {
    float2* op = (float2*)out;
    int tid  = threadIdx.x;
    int wv   = tid >> 6;          // wave 0..3
    int lane = tid & 63;
    int half = lane >> 5;         // node slot within wave
    int l    = lane & 31;         // column pair index
    float2 bb = make_float2(0.f, 0.f);
    if (bias) bb = ((const float2*)bias)[l];
    float2 s = make_float2(0.f, 0.f), q = make_float2(0.f, 0.f);

    for (int d0 = blockIdx.x * 8; d0 < n; d0 += gridDim.x * 8) {
        int d = d0 + wv * 2 + half;
        if (d < n) {
            float di = dinv[d];
            float sl = di * di;
            unsigned vs = hb[d * 32 + l];
            float2 acc;
            acc.x = fmaf(__uint_as_float(vs << 16),          sl, bb.x);
            acc.y = fmaf(__uint_as_float(vs & 0xffff0000u),  sl, bb.y);
            int k  = rowptr[d];
            int k1 = rowptr[d + 1];
            for (; k + 4 <= k1; k += 4) {
                float2 m0 = edata[k + 0];
                float2 m1 = edata[k + 1];
                float2 m2 = edata[k + 2];
                float2 m3 = edata[k + 3];
                unsigned v0 = hb[__float_as_int(m0.x) * 32 + l];
                unsigned v1 = hb[__float_as_int(m1.x) * 32 + l];
                unsigned v2 = hb[__float_as_int(m2.x) * 32 + l];
                unsigned v3 = hb[__float_as_int(m3.x) * 32 + l];
                acc.x = fmaf(__uint_as_float(v0 << 16),         m0.y, acc.x);
                acc.y = fmaf(__uint_as_float(v0 & 0xffff0000u), m0.y, acc.y);
                acc.x = fmaf(__uint_as_float(v1 << 16),         m1.y, acc.x);
                acc.y = fmaf(__uint_as_float(v1 & 0xffff0000u), m1.y, acc.y);
                acc.x = fmaf(__uint_as_float(v2 << 16),         m2.y, acc.x);
                acc.y = fmaf(__uint_as_float(v2 & 0xffff0000u), m2.y, acc.y);
                acc.x = fmaf(__uint_as_float(v3 << 16),         m3.y, acc.x);
                acc.y = fmaf(__uint_as_float(v3 & 0xffff0000u), m3.y, acc.y);
            }
            for (; k < k1; ++k) {
                float2 m = edata[k];
                unsigned v = hb[__float_as_int(m.x) * 32 + l];
                acc.x = fmaf(__uint_as_float(v << 16),         m.y, acc.x);
                acc.y = fmaf(__uint_as_float(v & 0xffff0000u), m.y, acc.y);
            }
            op[d * 32 + l] = acc;
            if (STATS) {
                s.x += acc.x; s.y += acc.y;
                q.x = fmaf(acc.x, acc.x, q.x);
                q.y = fmaf(acc.y, acc.y, q.y);
            }
        }
    }
    if (STATS) {
        __shared__ float2 ls[4][2][32];
        __shared__ float2 lq[4][2][32];
        ls[wv][half][l] = s;
        lq[wv][half][l] = q;
        __syncthreads();
        if (tid < 32) {
            float2 S = make_float2(0.f, 0.f), Q = make_float2(0.f, 0.f);
#pragma unroll
            for (int w2 = 0; w2 < 4; ++w2)
#pragma unroll
                for (int hh = 0; hh < 2; ++hh) {
                    S.x += ls[w2][hh][tid].x; S.y += ls[w2][hh][tid].y;
                    Q.x += lq[w2][hh][tid].x; Q.y += lq[w2][hh][tid].y;
                }
            atomicAdd(&stats[2 * tid],     S.x);
            atomicAdd(&stats[2 * tid + 1], S.y);
            atomicAdd(&stats[64 + 2 * tid],     Q.x);
            atomicAdd(&stats[64 + 2 * tid + 1], Q.y);
        }
    }
}

// stats -> (scale, shift):  scale = gamma*rsqrt(var+eps), shift = beta - mean*scale
// (b1 cancels: BN subtracts the column mean.)
__global__ void k_finalize(float* __restrict__ stats, const float* __restrict__ gamma,
                           const float* __restrict__ beta, float inv_n) {
    int j = threadIdx.x;
    if (j < 64) {
        float mean = stats[j] * inv_n;
        float var  = stats[64 + j] * inv_n - mean * mean;
        float sc   = gamma[j] * rsqrtf(var + EPS);
        stats[j]      = sc;
        stats[64 + j] = beta[j] - mean * sc;
    }
}

extern "C" void kernel_launch(void* const* d_in, const int* in_sizes, int n_in,
                              void* d_out, int out_size, void* d_ws, size_t ws_size,
                              hipStream_t stream) {
    const float* x     = (const float*)d_in[0];
    const int*   ei    = (const int*)d_in[1];
    const float* ew    = (const float*)d_in[2];
    const float* W1    = (const float*)d_in[3];
    // d_in[4] = b1 : cancels exactly in BatchNorm — unused.
    const float* gamma = (const float*)d_in[5];
    const float* beta  = (const float*)d_in[6];
    const float* W2    = (const float*)d_in[7];
    const float* b2    = (const float*)d_in[8];
    float*       out   = (float*)d_out;

    const int N = in_sizes[0] / D;
    const int E = in_sizes[2];
    const int* src = ei;
    const int* dst = ei + E;

    // ws layout (edata first for 8B alignment)
    float2*   edata  = (float2*)d_ws;                  // E float2
    unsigned* hb     = (unsigned*)(edata + E);         // N*32 packed bf16x2 (h1/h2)
    float*    agg1   = (float*)(hb + (size_t)N * 32);  // N*D fp32
    float*    dinv   = agg1 + (size_t)N * D;           // N
    float*    stats  = dinv + N;                       // 128
    int*      cnt    = (int*)(stats + 128);            // N
    int*      rowptr = cnt + N;                        // N+1
    int*      cursor = rowptr + N + 1;                 // N (also incl-scan temp)
    int*      bsum   = cursor + N;                     // 512

    const int nb_n = (N + 255) / 256;
    const int nb_e = (E + 255) / 256;

    k_init<<<nb_n, 256, 0, stream>>>(dinv, cnt, stats, N);
    k_degcnt<<<nb_e, 256, 0, stream>>>(dst, ew, dinv, cnt, E);
    k_dinv<<<nb_n, 256, 0, stream>>>(dinv, N);

    k_scan1<<<nb_n, 256, 0, stream>>>(cnt, cursor, bsum, N);   // cursor holds incl
    k_scan2<<<1, 512, 0, stream>>>(bsum, nb_n);
    k_scan3<<<nb_n, 256, 0, stream>>>(cnt, cursor, bsum, rowptr, cursor, N, E);
    k_fill<<<nb_e, 256, 0, stream>>>(src, dst, ew, dinv, cursor, edata, E);

    k_gemm<false><<<2048, 256, 0, stream>>>(x, W1, nullptr, hb, N);
    k_agg<true><<<2048, 256, 0, stream>>>(hb, edata, rowptr, dinv, nullptr, agg1, stats, N);
    k_finalize<<<1, 64, 0, stream>>>(stats, gamma, beta, 1.0f / (float)N);

    // h2 = relu(BN(agg1)) @ W2 — overwrites hb
    k_gemm<true><<<2048, 256, 0, stream>>>(agg1, W2, stats, hb, N);
    k_agg<false><<<2048, 256, 0, stream>>>(hb, edata, rowptr, dinv, b2, out, nullptr, N);
}

// Round 10
// 469.268 us; speedup vs baseline: 2.1417x; 1.2062x over previous
//
#include <hip/hip_runtime.h>

#define D 64
#define EPS 1e-5f
#define FP_SCALE 1099511627776.0f   // 2^40

// RTNE float->bf16 (finite values)
static __device__ __forceinline__ unsigned f2bf(float f) {
    unsigned u = __float_as_uint(f);
    unsigned r = ((u >> 16) & 1u) + 0x7fffu;
    return (u + r) >> 16;
}

// packed=0, stats=0
__global__ void k_init(unsigned long long* __restrict__ packed,
                       float* __restrict__ stats, int n) {
    int i = blockIdx.x * 256 + threadIdx.x;
    if (i < n) packed[i] = 0ull;
    if (i < 128) stats[i] = 0.0f;
}

// one u64 atomic per edge: top 12 bits count, low 52 bits fixed-point sum(w).
// Returned old value's top bits = this edge's rank within its dst row.
__global__ void k_cnt(const int* __restrict__ dst, const float* __restrict__ w,
                      unsigned long long* __restrict__ packed,
                      int* __restrict__ rank, int E) {
    int e = blockIdx.x * 256 + threadIdx.x;
    if (e < E) {
        unsigned long long v = (1ull << 52) |
            (unsigned long long)(w[e] * FP_SCALE);
        unsigned long long old = atomicAdd(&packed[dst[e]], v);
        rank[e] = (int)(old >> 52);
    }
}

// dinv = rsqrt(1 + unpack(wsum))
__global__ void k_deg(const unsigned long long* __restrict__ packed,
                      float* __restrict__ dinv, int n) {
    int i = blockIdx.x * 256 + threadIdx.x;
    if (i < n) {
        float wsum = (float)(packed[i] & ((1ull << 52) - 1ull)) * (1.0f / FP_SCALE);
        dinv[i] = rsqrtf(1.0f + wsum);
    }
}

// ---- exclusive scan of counts (from packed>>52) -> rowptr[N+1] ----
__global__ void k_scan1(const unsigned long long* __restrict__ packed,
                        int* __restrict__ incl, int* __restrict__ bsum, int n) {
    __shared__ int sm[256];
    int i = blockIdx.x * 256 + threadIdx.x;
    int v = (i < n) ? (int)(packed[i] >> 52) : 0;
    sm[threadIdx.x] = v;
    __syncthreads();
    for (int off = 1; off < 256; off <<= 1) {
        int t = 0;
        if (threadIdx.x >= off) t = sm[threadIdx.x - off];
        __syncthreads();
        if (threadIdx.x >= off) sm[threadIdx.x] += t;
        __syncthreads();
    }
    if (i < n) incl[i] = sm[threadIdx.x];
    if (threadIdx.x == 255) bsum[blockIdx.x] = sm[255];
}

__global__ void k_scan2(int* __restrict__ bsum, int nb) {
    __shared__ int sm[512];
    int v = (threadIdx.x < nb) ? bsum[threadIdx.x] : 0;
    sm[threadIdx.x] = v;
    __syncthreads();
    for (int off = 1; off < 512; off <<= 1) {
        int t = 0;
        if (threadIdx.x >= off) t = sm[threadIdx.x - off];
        __syncthreads();
        if (threadIdx.x >= off) sm[threadIdx.x] += t;
        __syncthreads();
    }
    if (threadIdx.x < nb) bsum[threadIdx.x] = sm[threadIdx.x] - v;  // exclusive
}

__global__ void k_scan3(const unsigned long long* __restrict__ packed,
                        const int* __restrict__ incl, const int* __restrict__ boff,
                        int* __restrict__ rowptr, int n, int E) {
    int i = blockIdx.x * 256 + threadIdx.x;
    if (i < n) {
        int c = (int)(packed[i] >> 52);
        rowptr[i] = incl[i] - c + boff[blockIdx.x];
        if (i == n - 1) rowptr[n] = E;
    }
}

// fill CSR payload without atomics: p = rowptr[dst] + rank
__global__ void k_fill(const int* __restrict__ src, const int* __restrict__ dst,
                       const float* __restrict__ w, const float* __restrict__ dinv,
                       const int* __restrict__ rowptr, const int* __restrict__ rank,
                       float2* __restrict__ edata, int E) {
    int e = blockIdx.x * 256 + threadIdx.x;
    if (e < E) {
        int s = src[e], d = dst[e];
        edata[rowptr[d] + rank[e]] =
            make_float2(__int_as_float(s), dinv[s] * w[e] * dinv[d]);
    }
}

// out = x @ W -> packed bf16x2 rows (32 uints per node), optionally with fused
// BN(scale,shift)+ReLU on input rows. Each thread computes 2 adjacent columns;
// 8 nodes per block-iteration.
template <bool BN>
__global__ void k_gemm(const float* __restrict__ x, const float* __restrict__ W,
                       const float* __restrict__ stats, unsigned* __restrict__ outb,
                       int n) {
    __shared__ float Wl[D][D];     // Wl[k][j]
    __shared__ float xs[8][D];
    int tid = threadIdx.x;
    int l   = tid & 31;            // column pair index (cols 2l, 2l+1)
    int ns  = tid >> 5;            // node slot 0..7
    for (int t = tid; t < D * D; t += 256) Wl[t >> 6][t & 63] = W[t];
    __syncthreads();
    for (int base = blockIdx.x * 8; base < n; base += gridDim.x * 8) {
        __syncthreads();           // previous iteration's xs reads done
        for (int t = tid; t < 8 * D; t += 256) {
            int r = t >> 6, c = t & 63;
            int node = base + r;
            float v = 0.f;
            if (node < n) {
                v = x[node * D + c];
                if (BN) v = fmaxf(fmaf(v, stats[c], stats[64 + c]), 0.f);
            }
            xs[r][c] = v;
        }
        __syncthreads();
        int node = base + ns;
        if (node < n) {
            float a0 = 0.f, a1 = 0.f;
#pragma unroll
            for (int k = 0; k < D; ++k) {
                float xv  = xs[ns][k];
                float2 wp = ((const float2*)Wl[k])[l];
                a0 = fmaf(xv, wp.x, a0);
                a1 = fmaf(xv, wp.y, a1);
            }
            outb[node * 32 + l] = f2bf(a0) | (f2bf(a1) << 16);
        }
    }
}

// gather-accumulate per dst node from packed-bf16 h: self-loop + bias + CSR
// edges; optional BN stats. 2 nodes per wave (half-wave each, one uint = 2
// bf16 cols per lane), edge loop unrolled x4.
template <bool STATS>
__global__ void k_agg(const unsigned* __restrict__ hb, const float2* __restrict__ edata,
                      const int* __restrict__ rowptr, const float* __restrict__ dinv,
                      const float* __restrict__ bias, float* __restrict__ out,
                      float* __restrict__ stats, int n) {
    float2* op = (float2*)out;
    int tid  = threadIdx.x;
    int wv   = tid >> 6;          // wave 0..3
    int lane = tid & 63;
    int half = lane >> 5;         // node slot within wave
    int l    = lane & 31;         // column pair index
    float2 bb = make_float2(0.f, 0.f);
    if (bias) bb = ((const float2*)bias)[l];
    float2 s = make_float2(0.f, 0.f), q = make_float2(0.f, 0.f);

    for (int d0 = blockIdx.x * 8; d0 < n; d0 += gridDim.x * 8) {
        int d = d0 + wv * 2 + half;
        if (d < n) {
            float di = dinv[d];
            float sl = di * di;
            unsigned vs = hb[d * 32 + l];
            float2 acc;
            acc.x = fmaf(__uint_as_float(vs << 16),          sl, bb.x);
            acc.y = fmaf(__uint_as_float(vs & 0xffff0000u),  sl, bb.y);
            int k  = rowptr[d];
            int k1 = rowptr[d + 1];
            for (; k + 4 <= k1; k += 4) {
                float2 m0 = edata[k + 0];
                float2 m1 = edata[k + 1];
                float2 m2 = edata[k + 2];
                float2 m3 = edata[k + 3];
                unsigned v0 = hb[__float_as_int(m0.x) * 32 + l];
                unsigned v1 = hb[__float_as_int(m1.x) * 32 + l];
                unsigned v2 = hb[__float_as_int(m2.x) * 32 + l];
                unsigned v3 = hb[__float_as_int(m3.x) * 32 + l];
                acc.x = fmaf(__uint_as_float(v0 << 16),         m0.y, acc.x);
                acc.y = fmaf(__uint_as_float(v0 & 0xffff0000u), m0.y, acc.y);
                acc.x = fmaf(__uint_as_float(v1 << 16),         m1.y, acc.x);
                acc.y = fmaf(__uint_as_float(v1 & 0xffff0000u), m1.y, acc.y);
                acc.x = fmaf(__uint_as_float(v2 << 16),         m2.y, acc.x);
                acc.y = fmaf(__uint_as_float(v2 & 0xffff0000u), m2.y, acc.y);
                acc.x = fmaf(__uint_as_float(v3 << 16),         m3.y, acc.x);
                acc.y = fmaf(__uint_as_float(v3 & 0xffff0000u), m3.y, acc.y);
            }
            for (; k < k1; ++k) {
                float2 m = edata[k];
                unsigned v = hb[__float_as_int(m.x) * 32 + l];
                acc.x = fmaf(__uint_as_float(v << 16),         m.y, acc.x);
                acc.y = fmaf(__uint_as_float(v & 0xffff0000u), m.y, acc.y);
            }
            op[d * 32 + l] = acc;
            if (STATS) {
                s.x += acc.x; s.y += acc.y;
                q.x = fmaf(acc.x, acc.x, q.x);
                q.y = fmaf(acc.y, acc.y, q.y);
            }
        }
    }
    if (STATS) {
        __shared__ float2 ls[4][2][32];
        __shared__ float2 lq[4][2][32];
        ls[wv][half][l] = s;
        lq[wv][half][l] = q;
        __syncthreads();
        if (tid < 32) {
            float2 S = make_float2(0.f, 0.f), Q = make_float2(0.f, 0.f);
#pragma unroll
            for (int w2 = 0; w2 < 4; ++w2)
#pragma unroll
                for (int hh = 0; hh < 2; ++hh) {
                    S.x += ls[w2][hh][tid].x; S.y += ls[w2][hh][tid].y;
                    Q.x += lq[w2][hh][tid].x; Q.y += lq[w2][hh][tid].y;
                }
            atomicAdd(&stats[2 * tid],     S.x);
            atomicAdd(&stats[2 * tid + 1], S.y);
            atomicAdd(&stats[64 + 2 * tid],     Q.x);
            atomicAdd(&stats[64 + 2 * tid + 1], Q.y);
        }
    }
}

// stats -> (scale, shift):  scale = gamma*rsqrt(var+eps), shift = beta - mean*scale
// (b1 cancels: BN subtracts the column mean.)
__global__ void k_finalize(float* __restrict__ stats, const float* __restrict__ gamma,
                           const float* __restrict__ beta, float inv_n) {
    int j = threadIdx.x;
    if (j < 64) {
        float mean = stats[j] * inv_n;
        float var  = stats[64 + j] * inv_n - mean * mean;
        float sc   = gamma[j] * rsqrtf(var + EPS);
        stats[j]      = sc;
        stats[64 + j] = beta[j] - mean * sc;
    }
}

extern "C" void kernel_launch(void* const* d_in, const int* in_sizes, int n_in,
                              void* d_out, int out_size, void* d_ws, size_t ws_size,
                              hipStream_t stream) {
    const float* x     = (const float*)d_in[0];
    const int*   ei    = (const int*)d_in[1];
    const float* ew    = (const float*)d_in[2];
    const float* W1    = (const float*)d_in[3];
    // d_in[4] = b1 : cancels exactly in BatchNorm — unused.
    const float* gamma = (const float*)d_in[5];
    const float* beta  = (const float*)d_in[6];
    const float* W2    = (const float*)d_in[7];
    const float* b2    = (const float*)d_in[8];
    float*       out   = (float*)d_out;

    const int N = in_sizes[0] / D;
    const int E = in_sizes[2];
    const int* src = ei;
    const int* dst = ei + E;

    // ws layout (8B-aligned chunks first)
    float2*             edata  = (float2*)d_ws;                    // E float2
    unsigned long long* packed = (unsigned long long*)(edata + E); // N u64
    unsigned*           hb     = (unsigned*)(packed + N);          // N*32 bf16x2
    float*              agg1   = (float*)(hb + (size_t)N * 32);    // N*D fp32
    float*              dinv   = agg1 + (size_t)N * D;             // N
    float*              stats  = dinv + N;                         // 128
    int*                rowptr = (int*)(stats + 128);              // N+1
    int*                tmp    = rowptr + N + 1;                   // N (incl scan)
    int*                rank   = tmp + N;                          // E
    int*                bsum   = rank + E;                         // 512

    const int nb_n = (N + 255) / 256;
    const int nb_e = (E + 255) / 256;

    k_init<<<nb_n, 256, 0, stream>>>(packed, stats, N);
    k_cnt<<<nb_e, 256, 0, stream>>>(dst, ew, packed, rank, E);
    k_deg<<<nb_n, 256, 0, stream>>>(packed, dinv, N);

    k_scan1<<<nb_n, 256, 0, stream>>>(packed, tmp, bsum, N);
    k_scan2<<<1, 512, 0, stream>>>(bsum, nb_n);
    k_scan3<<<nb_n, 256, 0, stream>>>(packed, tmp, bsum, rowptr, N, E);
    k_fill<<<nb_e, 256, 0, stream>>>(src, dst, ew, dinv, rowptr, rank, edata, E);

    k_gemm<false><<<2048, 256, 0, stream>>>(x, W1, nullptr, hb, N);
    k_agg<true><<<2048, 256, 0, stream>>>(hb, edata, rowptr, dinv, nullptr, agg1, stats, N);
    k_finalize<<<1, 64, 0, stream>>>(stats, gamma, beta, 1.0f / (float)N);

    // h2 = relu(BN(agg1)) @ W2 — overwrites hb
    k_gemm<true><<<2048, 256, 0, stream>>>(agg1, W2, stats, hb, N);
    k_agg<false><<<2048, 256, 0, stream>>>(hb, edata, rowptr, dinv, b2, out, nullptr, N);
}

// Round 11
// 422.084 us; speedup vs baseline: 2.3811x; 1.1118x over previous
//
#include <hip/hip_runtime.h>

#define D 64
#define EPS 1e-5f
#define FP_SCALE 1099511627776.0f   // 2^40

// RTNE float->bf16 (finite values)
static __device__ __forceinline__ unsigned f2bf(float f) {
    unsigned u = __float_as_uint(f);
    unsigned r = ((u >> 16) & 1u) + 0x7fffu;
    return (u + r) >> 16;
}

// packed=0, stats=0
__global__ void k_init(unsigned long long* __restrict__ packed,
                       float* __restrict__ stats, int n) {
    int i = blockIdx.x * 256 + threadIdx.x;
    if (i < n) packed[i] = 0ull;
    if (i < 128) stats[i] = 0.0f;
}

// one u64 atomic per edge: top 12 bits count, low 52 bits fixed-point sum(w).
// Returned old value's top bits = this edge's rank within its dst row.
__global__ void k_cnt(const int* __restrict__ dst, const float* __restrict__ w,
                      unsigned long long* __restrict__ packed,
                      int* __restrict__ rank, int E) {
    int e = blockIdx.x * 256 + threadIdx.x;
    if (e < E) {
        unsigned long long v = (1ull << 52) |
            (unsigned long long)(w[e] * FP_SCALE);
        unsigned long long old = atomicAdd(&packed[dst[e]], v);
        rank[e] = (int)(old >> 52);
    }
}

// dinv = rsqrt(1 + unpack(wsum))
__global__ void k_deg(const unsigned long long* __restrict__ packed,
                      float* __restrict__ dinv, int n) {
    int i = blockIdx.x * 256 + threadIdx.x;
    if (i < n) {
        float wsum = (float)(packed[i] & ((1ull << 52) - 1ull)) * (1.0f / FP_SCALE);
        dinv[i] = rsqrtf(1.0f + wsum);
    }
}

// ---- exclusive scan of counts (from packed>>52) -> rowptr[N+1] ----
__global__ void k_scan1(const unsigned long long* __restrict__ packed,
                        int* __restrict__ incl, int* __restrict__ bsum, int n) {
    __shared__ int sm[256];
    int i = blockIdx.x * 256 + threadIdx.x;
    int v = (i < n) ? (int)(packed[i] >> 52) : 0;
    sm[threadIdx.x] = v;
    __syncthreads();
    for (int off = 1; off < 256; off <<= 1) {
        int t = 0;
        if (threadIdx.x >= off) t = sm[threadIdx.x - off];
        __syncthreads();
        if (threadIdx.x >= off) sm[threadIdx.x] += t;
        __syncthreads();
    }
    if (i < n) incl[i] = sm[threadIdx.x];
    if (threadIdx.x == 255) bsum[blockIdx.x] = sm[255];
}

__global__ void k_scan2(int* __restrict__ bsum, int nb) {
    __shared__ int sm[512];
    int v = (threadIdx.x < nb) ? bsum[threadIdx.x] : 0;
    sm[threadIdx.x] = v;
    __syncthreads();
    for (int off = 1; off < 512; off <<= 1) {
        int t = 0;
        if (threadIdx.x >= off) t = sm[threadIdx.x - off];
        __syncthreads();
        if (threadIdx.x >= off) sm[threadIdx.x] += t;
        __syncthreads();
    }
    if (threadIdx.x < nb) bsum[threadIdx.x] = sm[threadIdx.x] - v;  // exclusive
}

__global__ void k_scan3(const unsigned long long* __restrict__ packed,
                        const int* __restrict__ incl, const int* __restrict__ boff,
                        int* __restrict__ rowptr, int n, int E) {
    int i = blockIdx.x * 256 + threadIdx.x;
    if (i < n) {
        int c = (int)(packed[i] >> 52);
        rowptr[i] = incl[i] - c + boff[blockIdx.x];
        if (i == n - 1) rowptr[n] = E;
    }
}

// fill CSR payload without atomics: p = rowptr[dst] + rank
__global__ void k_fill(const int* __restrict__ src, const int* __restrict__ dst,
                       const float* __restrict__ w, const float* __restrict__ dinv,
                       const int* __restrict__ rowptr, const int* __restrict__ rank,
                       float2* __restrict__ edata, int E) {
    int e = blockIdx.x * 256 + threadIdx.x;
    if (e < E) {
        int s = src[e], d = dst[e];
        edata[rowptr[d] + rank[e]] =
            make_float2(__int_as_float(s), dinv[s] * w[e] * dinv[d]);
    }
}

// out = x @ W -> packed bf16x2 rows (32 uints per node), optionally with fused
// BN(scale,shift)+ReLU on input rows. Each thread computes 2 adjacent columns;
// 8 nodes per block-iteration.
template <bool BN>
__global__ void k_gemm(const float* __restrict__ x, const float* __restrict__ W,
                       const float* __restrict__ stats, unsigned* __restrict__ outb,
                       int n) {
    __shared__ float Wl[D][D];     // Wl[k][j]
    __shared__ float xs[8][D];
    int tid = threadIdx.x;
    int l   = tid & 31;            // column pair index (cols 2l, 2l+1)
    int ns  = tid >> 5;            // node slot 0..7
    for (int t = tid; t < D * D; t += 256) Wl[t >> 6][t & 63] = W[t];
    __syncthreads();
    for (int base = blockIdx.x * 8; base < n; base += gridDim.x * 8) {
        __syncthreads();           // previous iteration's xs reads done
        for (int t = tid; t < 8 * D; t += 256) {
            int r = t >> 6, c = t & 63;
            int node = base + r;
            float v = 0.f;
            if (node < n) {
                v = x[node * D + c];
                if (BN) v = fmaxf(fmaf(v, stats[c], stats[64 + c]), 0.f);
            }
            xs[r][c] = v;
        }
        __syncthreads();
        int node = base + ns;
        if (node < n) {
            float a0 = 0.f, a1 = 0.f;
#pragma unroll
            for (int k = 0; k < D; ++k) {
                float xv  = xs[ns][k];
                float2 wp = ((const float2*)Wl[k])[l];
                a0 = fmaf(xv, wp.x, a0);
                a1 = fmaf(xv, wp.y, a1);
            }
            outb[node * 32 + l] = f2bf(a0) | (f2bf(a1) << 16);
        }
    }
}

// unpack uint4 (8 bf16) and accumulate with weight
#define ACC8(v, wgt)                                                  \
    acc[0] = fmaf(__uint_as_float((v).x << 16),         (wgt), acc[0]); \
    acc[1] = fmaf(__uint_as_float((v).x & 0xffff0000u), (wgt), acc[1]); \
    acc[2] = fmaf(__uint_as_float((v).y << 16),         (wgt), acc[2]); \
    acc[3] = fmaf(__uint_as_float((v).y & 0xffff0000u), (wgt), acc[3]); \
    acc[4] = fmaf(__uint_as_float((v).z << 16),         (wgt), acc[4]); \
    acc[5] = fmaf(__uint_as_float((v).z & 0xffff0000u), (wgt), acc[5]); \
    acc[6] = fmaf(__uint_as_float((v).w << 16),         (wgt), acc[6]); \
    acc[7] = fmaf(__uint_as_float((v).w & 0xffff0000u), (wgt), acc[7]);

// gather-accumulate per dst node from packed-bf16 h.
// 8 nodes per wave: 8 lanes per node, each lane gathers uint4 (16B of the
// 128B row) -> one gather instruction covers 8 edges (4x fewer addresses
// per edge than 2-node layout). Edge loop unrolled x2 per slot.
template <bool STATS>
__global__ void k_agg(const uint4* __restrict__ hb4, const float2* __restrict__ edata,
                      const int* __restrict__ rowptr, const float* __restrict__ dinv,
                      const float* __restrict__ bias, float* __restrict__ out,
                      float* __restrict__ stats, int n) {
    int tid  = threadIdx.x;
    int wv   = tid >> 6;          // wave 0..3
    int lane = tid & 63;
    int slot = lane >> 3;         // node slot 0..7 within wave
    int c    = lane & 7;          // 16B chunk (cols 8c..8c+7)
    int d    = blockIdx.x * 32 + wv * 8 + slot;

    float acc[8] = {0.f, 0.f, 0.f, 0.f, 0.f, 0.f, 0.f, 0.f};
    int k = 0, k1 = 0;
    if (d < n) { k = rowptr[d]; k1 = rowptr[d + 1]; }

    while (__any(k < k1)) {
        bool a0 = k < k1;
        bool a1 = k + 1 < k1;
        float2 m0, m1;
        uint4  v0, v1;
        if (a0) { m0 = edata[k];     v0 = hb4[__float_as_int(m0.x) * 8 + c]; }
        if (a1) { m1 = edata[k + 1]; v1 = hb4[__float_as_int(m1.x) * 8 + c]; }
        if (a0) { ACC8(v0, m0.y) }
        if (a1) { ACC8(v1, m1.y) }
        k += 2;
    }

    if (d < n) {
        float di = dinv[d];
        float sl = di * di;
        uint4 vs = hb4[d * 8 + c];
        ACC8(vs, sl)
        if (bias) {
            float4 b0 = ((const float4*)bias)[2 * c];
            float4 b1 = ((const float4*)bias)[2 * c + 1];
            acc[0] += b0.x; acc[1] += b0.y; acc[2] += b0.z; acc[3] += b0.w;
            acc[4] += b1.x; acc[5] += b1.y; acc[6] += b1.z; acc[7] += b1.w;
        }
        float4* op = (float4*)out;
        op[d * 16 + 2 * c]     = make_float4(acc[0], acc[1], acc[2], acc[3]);
        op[d * 16 + 2 * c + 1] = make_float4(acc[4], acc[5], acc[6], acc[7]);
    }

    if (STATS) {
        float s[8], q[8];
#pragma unroll
        for (int i = 0; i < 8; ++i) {
            float a = (d < n) ? acc[i] : 0.f;
            s[i] = a;
            q[i] = a * a;
        }
        // reduce across the 8 slots (lane bits 3..5)
#pragma unroll
        for (int m = 8; m <= 32; m <<= 1) {
#pragma unroll
            for (int i = 0; i < 8; ++i) {
                s[i] += __shfl_xor(s[i], m);
                q[i] += __shfl_xor(q[i], m);
            }
        }
        __shared__ float ls[4][8][8];
        __shared__ float lq[4][8][8];
        if (slot == 0) {
#pragma unroll
            for (int i = 0; i < 8; ++i) { ls[wv][c][i] = s[i]; lq[wv][c][i] = q[i]; }
        }
        __syncthreads();
        if (tid < 64) {
            int cc = tid >> 3, r = tid & 7;
            float S = ls[0][cc][r] + ls[1][cc][r] + ls[2][cc][r] + ls[3][cc][r];
            float Q = lq[0][cc][r] + lq[1][cc][r] + lq[2][cc][r] + lq[3][cc][r];
            atomicAdd(&stats[8 * cc + r],      S);
            atomicAdd(&stats[64 + 8 * cc + r], Q);
        }
    }
}

// stats -> (scale, shift):  scale = gamma*rsqrt(var+eps), shift = beta - mean*scale
// (b1 cancels: BN subtracts the column mean.)
__global__ void k_finalize(float* __restrict__ stats, const float* __restrict__ gamma,
                           const float* __restrict__ beta, float inv_n) {
    int j = threadIdx.x;
    if (j < 64) {
        float mean = stats[j] * inv_n;
        float var  = stats[64 + j] * inv_n - mean * mean;
        float sc   = gamma[j] * rsqrtf(var + EPS);
        stats[j]      = sc;
        stats[64 + j] = beta[j] - mean * sc;
    }
}

extern "C" void kernel_launch(void* const* d_in, const int* in_sizes, int n_in,
                              void* d_out, int out_size, void* d_ws, size_t ws_size,
                              hipStream_t stream) {
    const float* x     = (const float*)d_in[0];
    const int*   ei    = (const int*)d_in[1];
    const float* ew    = (const float*)d_in[2];
    const float* W1    = (const float*)d_in[3];
    // d_in[4] = b1 : cancels exactly in BatchNorm — unused.
    const float* gamma = (const float*)d_in[5];
    const float* beta  = (const float*)d_in[6];
    const float* W2    = (const float*)d_in[7];
    const float* b2    = (const float*)d_in[8];
    float*       out   = (float*)d_out;

    const int N = in_sizes[0] / D;
    const int E = in_sizes[2];
    const int* src = ei;
    const int* dst = ei + E;

    // ws layout (16B/8B-aligned chunks first)
    float2*             edata  = (float2*)d_ws;                    // E float2
    unsigned long long* packed = (unsigned long long*)(edata + E); // N u64
    unsigned*           hb     = (unsigned*)(packed + N);          // N*32 bf16x2
    float*              agg1   = (float*)(hb + (size_t)N * 32);    // N*D fp32
    float*              dinv   = agg1 + (size_t)N * D;             // N
    float*              stats  = dinv + N;                         // 128
    int*                rowptr = (int*)(stats + 128);              // N+1
    int*                tmp    = rowptr + N + 1;                   // N (incl scan)
    int*                rank   = tmp + N;                          // E
    int*                bsum   = rank + E;                         // 512

    const int nb_n = (N + 255) / 256;
    const int nb_e = (E + 255) / 256;
    const int nb_a = (N + 31) / 32;

    k_init<<<nb_n, 256, 0, stream>>>(packed, stats, N);
    k_cnt<<<nb_e, 256, 0, stream>>>(dst, ew, packed, rank, E);
    k_deg<<<nb_n, 256, 0, stream>>>(packed, dinv, N);

    k_scan1<<<nb_n, 256, 0, stream>>>(packed, tmp, bsum, N);
    k_scan2<<<1, 512, 0, stream>>>(bsum, nb_n);
    k_scan3<<<nb_n, 256, 0, stream>>>(packed, tmp, bsum, rowptr, N, E);
    k_fill<<<nb_e, 256, 0, stream>>>(src, dst, ew, dinv, rowptr, rank, edata, E);

    k_gemm<false><<<2048, 256, 0, stream>>>(x, W1, nullptr, hb, N);
    k_agg<true><<<nb_a, 256, 0, stream>>>((const uint4*)hb, edata, rowptr, dinv,
                                          nullptr, agg1, stats, N);
    k_finalize<<<1, 64, 0, stream>>>(stats, gamma, beta, 1.0f / (float)N);

    // h2 = relu(BN(agg1)) @ W2 — overwrites hb
    k_gemm<true><<<2048, 256, 0, stream>>>(agg1, W2, stats, hb, N);
    k_agg<false><<<nb_a, 256, 0, stream>>>((const uint4*)hb, edata, rowptr, dinv,
                                           b2, out, nullptr, N);
}